// Round 22
// baseline (313.419 us; speedup 1.0000x reference)
//
#include <hip/hip_runtime.h>
#include <math.h>

#define NE 8
#define IN_C 192
#define HID 384
#define OUT_C 192
#define R_C 8
#define HW 16384
#define NPIX 65536
#define PPB 16384    // pixels per image
#define TNP 64       // pixels per moe block

typedef _Float16 h8_t __attribute__((ext_vector_type(8)));
typedef float f32x16 __attribute__((ext_vector_type(16)));

// A&S 7.1.26 erf (|abs err| <= 1.5e-7) -> exact-GELU within fp32 noise.
__device__ __forceinline__ float gelu_exact(float v) {
  float z  = v * 0.70710678118654752f;
  float az = fabsf(z);
  float t  = __builtin_amdgcn_rcpf(1.0f + 0.3275911f * az);
  float p  = ((((1.061405429f * t - 1.453152027f) * t + 1.421413741f) * t
               - 0.284496736f) * t + 0.254829592f) * t;
  float er = 1.0f - p * __expf(-z * z);
  er = copysignf(er, z);
  return 0.5f * v * (1.0f + er);
}

// ---------------------------------------------------------------------------
// x transpose helper (one image): xb [192][16384] fp32 -> dst [16384][192] f16
// ---------------------------------------------------------------------------
__device__ __forceinline__ void xt_block(const float* __restrict__ xb,
                                         _Float16* __restrict__ dst,
                                         int blk, int tid) {
  const int p = blk * 64 + (tid & 63);
  const int cq0 = tid >> 6;
#pragma unroll
  for (int cq = 0; cq < 6; ++cq) {
    int chq = cq * 4 + cq0;
    union { _Float16 h[8]; uint4 u; } pk;
#pragma unroll
    for (int j = 0; j < 8; ++j)
      pk.h[j] = (_Float16)xb[(size_t)(chq * 8 + j) * HW + p];
    *(uint4*)(dst + (size_t)p * 192 + chq * 8) = pk.u;
  }
}

// ---------------------------------------------------------------------------
// Fused prologue: blockIdx partitions three independent jobs.
//   [0, 2304): weight fp32 -> fp16 blob (consumption order, 48x12KB chunks,
//              chunk = [g:4][m:192][j:8], element (m, k0+8g+j))
//   [2304, 2560): router (LDS histogram + 1 global atomic per block/expert)
//   [2560, 3072): x transpose for pair 0 (img2 = blk>>8)
// ---------------------------------------------------------------------------
__global__ __launch_bounds__(256) void prologue_kernel(
    const float* __restrict__ W1, const float* __restrict__ W2,
    const float* __restrict__ W3, _Float16* __restrict__ Wb,
    const float* __restrict__ rin, const float* __restrict__ rW,
    const float* __restrict__ rb, int* __restrict__ counts,
    int* __restrict__ lists, float* __restrict__ gatev,
    const float* __restrict__ x, _Float16* __restrict__ xt) {
  const int bid = blockIdx.x;
  const int tid = threadIdx.x;

  __shared__ int lcount[NE];
  __shared__ int lbase[NE];

  if (bid < 2304) {
    // ---- cvt_blob ----
    int t = bid * 256 + tid;
    if (t >= NE * 73728) return;     // uint2 units: 48*1536 per expert
    int e = t / 73728, r = t % 73728;
    int cg = r / 1536, w = r % 1536;
    int j4 = w & 1, gm = w >> 1;
    int m = gm % 192, g = gm / 192;
    const float* src; int row, col, lda;
    if (cg < 6)       { src = W1 + (size_t)e * 73728;  row = m;       col = 32 * cg + 8 * g + 4 * j4; lda = 192; }
    else if (cg < 18) { int s = cg - 6;  int c = s >> 1, mh = s & 1;
                        src = W2 + (size_t)e * 147456; row = 192 * mh + m; col = 32 * c + 8 * g + 4 * j4; lda = 384; }
    else if (cg < 24) { int c = cg - 18;
                        src = W1 + (size_t)e * 73728;  row = 192 + m; col = 32 * c + 8 * g + 4 * j4; lda = 192; }
    else if (cg < 36) { int s = cg - 24; int c = s >> 1, mh = s & 1;
                        src = W2 + (size_t)e * 147456; row = 192 * mh + m; col = 192 + 32 * c + 8 * g + 4 * j4; lda = 384; }
    else              { int c = cg - 36;
                        src = W3 + (size_t)e * 73728;  row = m;       col = 32 * c + 8 * g + 4 * j4; lda = 384; }
    float4 v = *(const float4*)(src + (size_t)row * lda + col);
    union { _Float16 h4[4]; uint2 u; } cv;
    cv.h4[0] = (_Float16)v.x; cv.h4[1] = (_Float16)v.y;
    cv.h4[2] = (_Float16)v.z; cv.h4[3] = (_Float16)v.w;
    ((uint2*)Wb)[t] = cv.u;
  } else if (bid < 2560) {
    // ---- router ----
    const int pid = (bid - 2304) * 256 + tid;
    const int img = pid >> 14;
    const int p = pid & (PPB - 1);

    if (tid < NE) lcount[tid] = 0;
    __syncthreads();

    const float* rbase = rin + (size_t)img * R_C * HW + p;
    float r[R_C];
#pragma unroll
    for (int c = 0; c < R_C; ++c) r[c] = rbase[(size_t)c * HW];
    float lg[NE];
#pragma unroll
    for (int e = 0; e < NE; ++e) {
      float s = rb[e];
#pragma unroll
      for (int c = 0; c < R_C; ++c) s += rW[e * R_C + c] * r[c];
      lg[e] = s;
    }
    int e0 = 0; float l0 = lg[0];
#pragma unroll
    for (int e = 1; e < NE; ++e) { if (lg[e] > l0) { l0 = lg[e]; e0 = e; } }
    int e1 = -1; float l1 = -3.4e38f;
#pragma unroll
    for (int e = 0; e < NE; ++e) {
      if (e != e0 && lg[e] > l1) { l1 = lg[e]; e1 = e; }
    }
    float ex  = expf(l1 - l0);
    float inv = 1.0f / (1.0f + ex);
    float g0 = inv, g1 = ex * inv;

    int pos0 = atomicAdd(&lcount[e0], 1);
    int pos1 = atomicAdd(&lcount[e1], 1);
    __syncthreads();
    if (tid < NE) lbase[tid] = atomicAdd(&counts[tid * 4 + img], lcount[tid]);
    __syncthreads();

    int i0 = (e0 * 4 + img) * PPB + lbase[e0] + pos0;
    lists[i0] = p;
    gatev[i0] = g0;
    int i1 = (e1 * 4 + img) * PPB + lbase[e1] + pos1;
    lists[i1] = p | (1 << 14);
    gatev[i1] = g1;
  } else {
    // ---- xt for pair 0 ----
    const int b2 = bid - 2560;
    const int img2 = b2 >> 8;
    xt_block(x + (size_t)img2 * IN_C * HW,
             xt + (size_t)img2 * PPB * 192, b2 & 255, tid);
  }
}

// ---------------------------------------------------------------------------
// Stage one 12KB chunk with 384 threads: 2 uniform global_load_lds per wave
// (6 waves x 1024B per instruction). vmcnt cost = 2 per chunk, ALL waves.
// ---------------------------------------------------------------------------
__device__ __forceinline__ void stage_chunk(const char* __restrict__ g,
                                            char* lds, int tid, int wid) {
  __builtin_amdgcn_global_load_lds(
      (const __attribute__((address_space(1))) void*)(g + tid * 16),
      (__attribute__((address_space(3))) void*)(lds + wid * 1024), 16, 0, 0);
  __builtin_amdgcn_global_load_lds(
      (const __attribute__((address_space(1))) void*)(g + 6144 + tid * 16),
      (__attribute__((address_space(3))) void*)(lds + 6144 + wid * 1024), 16, 0, 0);
}

// Phase entry: chunk s ready (chunk s+1 stays in flight), then barrier.
__device__ __forceinline__ void pwait_u(bool last) {
  if (last) asm volatile("s_waitcnt vmcnt(0)" ::: "memory");
  else      asm volatile("s_waitcnt vmcnt(2)" ::: "memory");
  __builtin_amdgcn_s_barrier();
  __builtin_amdgcn_sched_barrier(0);
}

// 2 B-fragments (k-halves of a k=32 chunk) from LDS slot order [k8][64][8].
// 32x32x16 B map: col = nt*32 + (lane&31), k = kk*16 + 8*(lane>>5) + j.
__device__ __forceinline__ void read_Bk(const _Float16* __restrict__ Bsh, int kb4,
                                        int nt, int l31, int h, h8_t (&b)[2]) {
  b[0] = *(const h8_t*)(Bsh + (((size_t)(kb4 + h) * TNP) + nt * 32 + l31) * 8);
  b[1] = *(const h8_t*)(Bsh + (((size_t)(kb4 + 2 + h) * TNP) + nt * 32 + l31) * 8);
}

// One chunk: 2 m-tiles x 2 k-halves of v_mfma_f32_32x32x16_f16.
// A chunk [g:4][m:192][j:8] with g = kk*2 + h: row = mt*32+(lane&31),
// k = kk*16 + 8h + j  (identical (h,j)->k map as B: permutation cancels).
__device__ __forceinline__ void mfma_ph(const _Float16* __restrict__ A,
                                        const h8_t (&b)[2], int mt0,
                                        f32x16 (&acc)[2], int l31, int h) {
  __builtin_amdgcn_s_setprio(1);
#pragma unroll
  for (int t = 0; t < 2; ++t) {
    h8_t a0 = *(const h8_t*)(A + ((size_t)h * 192 + (mt0 + t) * 32 + l31) * 8);
    acc[t] = __builtin_amdgcn_mfma_f32_32x32x16_f16(a0, b[0], acc[t], 0, 0, 0);
    h8_t a1 = *(const h8_t*)(A + ((size_t)(2 + h) * 192 + (mt0 + t) * 32 + l31) * 8);
    acc[t] = __builtin_amdgcn_mfma_f32_32x32x16_f16(a1, b[1], acc[t], 0, 0, 0);
  }
  __builtin_amdgcn_s_setprio(0);
}

// gelu + fp16 pack -> LDS slot order. C/D: col = nt*32+(lane&31),
// row_local = mt*32 + (reg&3) + 8*(reg>>2) + 4*(lane>>5), reg = q*4+i.
__device__ __forceinline__ void act_store32(f32x16 (&acc)[2], const float* __restrict__ bias,
                                            _Float16* __restrict__ Dst, int mt0, int nt,
                                            int l31, int h) {
  const int n = nt * 32 + l31;
#pragma unroll
  for (int t = 0; t < 2; ++t) {
#pragma unroll
    for (int q = 0; q < 4; ++q) {
      int rb = (mt0 + t) * 32 + q * 8 + 4 * h;
      float4 bv = *(const float4*)(bias + rb);
      union { _Float16 hh[4]; uint2 u; } cv;
      cv.hh[0] = (_Float16)gelu_exact(acc[t][q * 4 + 0] + bv.x);
      cv.hh[1] = (_Float16)gelu_exact(acc[t][q * 4 + 1] + bv.y);
      cv.hh[2] = (_Float16)gelu_exact(acc[t][q * 4 + 2] + bv.z);
      cv.hh[3] = (_Float16)gelu_exact(acc[t][q * 4 + 3] + bv.w);
      *(uint2*)(Dst + (((size_t)(rb >> 3) * TNP) + n) * 8 + (rb & 7)) = cv.u;
    }
  }
}

// gated y -> fp16 dense store into ybuf[pidsl + c]
__device__ __forceinline__ void ybuf_store32(f32x16 (&acc)[2], const float* __restrict__ bias,
                                             _Float16* __restrict__ ybuf,
                                             const int* __restrict__ pidsl,
                                             const float* __restrict__ pg,
                                             int npt, int mt0, int nt, int l31, int h) {
  const int n = nt * 32 + l31;
  if (n >= npt) return;
  float gt = pg[n];
  _Float16* yb = ybuf + pidsl[n];
#pragma unroll
  for (int t = 0; t < 2; ++t) {
#pragma unroll
    for (int q = 0; q < 4; ++q) {
      int rb = (mt0 + t) * 32 + q * 8 + 4 * h;
      float4 bv = *(const float4*)(bias + rb);
      union { _Float16 hh[4]; uint2 u; } cv;
      cv.hh[0] = (_Float16)((acc[t][q * 4 + 0] + bv.x) * gt);
      cv.hh[1] = (_Float16)((acc[t][q * 4 + 1] + bv.y) * gt);
      cv.hh[2] = (_Float16)((acc[t][q * 4 + 2] + bv.z) * gt);
      cv.hh[3] = (_Float16)((acc[t][q * 4 + 3] + bv.w) * gt);
      *(uint2*)(yb + rb) = cv.u;
    }
  }
}

// ---------------------------------------------------------------------------
// Fused 3-layer MLP, 64-pixel tile, 6 waves (384 thr), 48 single-chunk phases
// over a 2x12KB ring; MFMA shape 32x32x16 (halved LDS bytes/MAC on A).
// Waves: 3 M-groups (2x 32-row tiles each) x 2 N-tiles. LDS 76.5KB ->
// 2 blocks/CU, 3 waves/SIMD (VGPR cap 168, acc 96 regs safe).
// Depth-1 prefetch invariant: the phase computing chunk c stages chunk c+2.
// ---------------------------------------------------------------------------
__global__ __launch_bounds__(384, 3) void moe_mfma_kernel(
    const _Float16* __restrict__ xt, const _Float16* __restrict__ Wb,
    const float* __restrict__ b1, const float* __restrict__ b2,
    const float* __restrict__ b3,
    const int* __restrict__ counts, const int* __restrict__ lists,
    const float* __restrict__ gatev, _Float16* __restrict__ ybuf, int pair) {
  const int e = blockIdx.x;
  const int img2 = blockIdx.y >> 8;
  const int tile = blockIdx.y & 255;
  const int img = pair * 2 + img2;
  const int cnt = counts[e * 4 + img];
  const int start = tile * TNP;
  if (start >= cnt) return;
  const int npt = min(TNP, cnt - start);

  __shared__ __align__(16) char smem[78336];
  _Float16* XB  = (_Float16*)smem;                 // [24][64][8] 24K
  _Float16* H1a = (_Float16*)(smem + 24576);       // [24][64][8] 24K
  _Float16* H2  = (_Float16*)smem;                 // [48][64][8] 48K alias
  char* RING   = smem + 49152;                     // 2 x 12K
  float* BIAS1 = (float*)(smem + 73728);
  float* BIAS2 = (float*)(smem + 75264);
  float* BIAS3 = (float*)(smem + 76800);
  int*   pp    = (int*)(smem + 77568);
  int*   pidsl = (int*)(smem + 77824);
  float* pg    = (float*)(smem + 78080);

  const int tid = threadIdx.x;
  const int lane = tid & 63;
  const int wid = tid >> 6;          // 0..5
  const int l31 = lane & 31;
  const int h = lane >> 5;           // k-half selector
  const int mt0 = (wid >> 1) * 2;    // m-tiles {mt0, mt0+1} of 6
  const int nt = wid & 1;            // n-tile 0/1

  // ---- prologue: lists, biases, x-gather ----
  if (tid < TNP) {
    int entry = 0; float gt = 0.0f;
    if (tid < npt) {
      entry = lists[(e * 4 + img) * PPB + start + tid];
      gt    = gatev[(e * 4 + img) * PPB + start + tid];
    }
    int p = entry & (PPB - 1);
    int slot = (entry >> 14) & 1;
    pp[tid] = img2 * PPB + p;
    pidsl[tid] = ((img2 * PPB + p) * 2 + slot) * 192;
    pg[tid] = gt;
  }
  for (int i = tid; i < 960; i += 384) {
    if (i < 384) BIAS1[i] = b1[e * HID + i];
    else if (i < 768) BIAS2[i - 384] = b2[e * HID + (i - 384)];
    else BIAS3[i - 768] = b3[e * OUT_C + (i - 768)];
  }
  __syncthreads();

  for (int i = tid; i < 24 * TNP; i += 384) {   // 4 iterations
    int n = i & (TNP - 1);
    int c16 = i >> 6;
    uint4 v = {0, 0, 0, 0};
    if (n < npt) v = *(const uint4*)(xt + (size_t)pp[n] * 192 + c16 * 8);
    *(uint4*)(XB + ((size_t)c16 * TNP + n) * 8) = v;
  }
  __syncthreads();   // drains gather vmem; only stage loads counted below

  const char* blob = (const char*)(Wb + (size_t)e * 294912);
  stage_chunk(blob, RING, tid, wid);
  stage_chunk(blob + 12288, RING + 12288, tid, wid);

  f32x16 acc1[2], acc2a[2], acc2b[2];
#pragma unroll
  for (int t = 0; t < 2; ++t) {
#pragma unroll
    for (int i = 0; i < 16; ++i) {
      acc1[t][i] = 0.f; acc2a[t][i] = 0.f; acc2b[t][i] = 0.f;
    }
  }

  h8_t b[2];

  // ---- seg A: chunks 0..5, L1 half0, B=XB kb4=4s ----
#pragma unroll
  for (int s = 0; s < 6; ++s) {
    pwait_u(false);
    read_Bk(XB, 4 * s, nt, l31, h, b);
    mfma_ph((const _Float16*)(RING + (s & 1) * 12288), b, mt0, acc1, l31, h);
    if (s == 5) {
      act_store32(acc1, BIAS1, H1a, mt0, nt, l31, h);
      asm volatile("s_waitcnt lgkmcnt(0)");
    }
    __builtin_amdgcn_sched_barrier(0);
    __builtin_amdgcn_s_barrier();
    __builtin_amdgcn_sched_barrier(0);
    stage_chunk(blob + (size_t)(s + 2) * 12288, RING + (s & 1) * 12288, tid, wid);
  }

  // ---- seg B: chunks 6..17, L2 kh0, B=H1a kb4=4*(s>>1), acc by mh=s&1 ----
#pragma unroll
  for (int s = 0; s < 12; ++s) {
    pwait_u(false);
    if ((s & 1) == 0) read_Bk(H1a, 4 * (s >> 1), nt, l31, h, b);
    mfma_ph((const _Float16*)(RING + (s & 1) * 12288), b, mt0,
            (s & 1) ? acc2b : acc2a, l31, h);
    __builtin_amdgcn_sched_barrier(0);
    __builtin_amdgcn_s_barrier();
    __builtin_amdgcn_sched_barrier(0);
    stage_chunk(blob + (size_t)(s + 8) * 12288, RING + (s & 1) * 12288, tid, wid);
  }

  // ---- seg C: chunks 18..23, L1 half1 (stage s+20) ----
#pragma unroll
  for (int t = 0; t < 2; ++t)
#pragma unroll
    for (int i = 0; i < 16; ++i) acc1[t][i] = 0.f;
#pragma unroll
  for (int s = 0; s < 6; ++s) {
    pwait_u(false);
    read_Bk(XB, 4 * s, nt, l31, h, b);
    mfma_ph((const _Float16*)(RING + (s & 1) * 12288), b, mt0, acc1, l31, h);
    if (s == 5) {
      act_store32(acc1, BIAS1 + 192, H1a, mt0, nt, l31, h);
      asm volatile("s_waitcnt lgkmcnt(0)");
    }
    __builtin_amdgcn_sched_barrier(0);
    __builtin_amdgcn_s_barrier();
    __builtin_amdgcn_sched_barrier(0);
    stage_chunk(blob + (size_t)(s + 20) * 12288, RING + (s & 1) * 12288, tid, wid);
  }

  // ---- seg D: chunks 24..35, L2 kh1 (stage s+26) ----
#pragma unroll
  for (int s = 0; s < 12; ++s) {
    pwait_u(false);
    if ((s & 1) == 0) read_Bk(H1a, 4 * (s >> 1), nt, l31, h, b);
    mfma_ph((const _Float16*)(RING + (s & 1) * 12288), b, mt0,
            (s & 1) ? acc2b : acc2a, l31, h);
    if (s == 11) {
      // h2 = gelu(acc2); H2 aliases XB (rows 0-191, dead) + H1a (rows 192+,
      // all reads completed before this phase's MFMA consumed reg B).
      act_store32(acc2a, BIAS2, H2, mt0, nt, l31, h);
      act_store32(acc2b, BIAS2, H2 + 192 * TNP * 8 / 8 * 0 + (size_t)24 * TNP * 8, mt0, nt, l31, h);
      asm volatile("s_waitcnt lgkmcnt(0)");
    }
    __builtin_amdgcn_sched_barrier(0);
    __builtin_amdgcn_s_barrier();
    __builtin_amdgcn_sched_barrier(0);
    stage_chunk(blob + (size_t)(s + 26) * 12288, RING + (s & 1) * 12288, tid, wid);
  }

  // ---- seg E: chunks 36..47, L3 over H2, kb4=4s (stage s+38, s<10) ----
#pragma unroll
  for (int t = 0; t < 2; ++t)
#pragma unroll
    for (int i = 0; i < 16; ++i) acc1[t][i] = 0.f;
#pragma unroll
  for (int s = 0; s < 12; ++s) {
    pwait_u(s == 11);
    read_Bk(H2, 4 * s, nt, l31, h, b);
    mfma_ph((const _Float16*)(RING + (s & 1) * 12288), b, mt0, acc1, l31, h);
    if (s < 10) {
      __builtin_amdgcn_sched_barrier(0);
      __builtin_amdgcn_s_barrier();
      __builtin_amdgcn_sched_barrier(0);
      stage_chunk(blob + (size_t)(s + 38) * 12288, RING + (s & 1) * 12288, tid, wid);
    }
  }

  ybuf_store32(acc1, BIAS3, ybuf, pidsl, pg, npt, mt0, nt, l31, h);
}

// ---------------------------------------------------------------------------
// Sum the two gated slot results per pixel, write out coalesced.
// If XTP1 != 0, blocks [512, 1024) additionally transpose x for pair 1.
// ---------------------------------------------------------------------------
__global__ __launch_bounds__(256) void sum_kernel(
    const _Float16* __restrict__ ybuf, float* __restrict__ out, int pair,
    const float* __restrict__ x, _Float16* __restrict__ xt, int xtp1) {
  __shared__ float ys[64][193];
  const int tid = threadIdx.x;

  if (xtp1 && blockIdx.x >= 512) {
    const int b2 = blockIdx.x - 512;
    const int img2 = b2 >> 8;
    xt_block(x + (size_t)(2 + img2) * IN_C * HW,
             xt + (size_t)img2 * PPB * 192, b2 & 255, tid);
    return;
  }

  const int img2 = blockIdx.x >> 8;
  const int p0 = (blockIdx.x & 255) * 64;
  const _Float16* yb = ybuf + (size_t)(img2 * PPB + p0) * 2 * 192;

  for (int t = tid; t < 64 * 48; t += 256) {
    int p = t / 48, c4 = t % 48;
    const uint2* y0 = (const uint2*)(yb + (size_t)p * 2 * 192) + c4;
    uint2 u0 = y0[0];
    uint2 u1 = y0[48];
    union { uint2 u; _Float16 h[4]; } a, b;
    a.u = u0; b.u = u1;
#pragma unroll
    for (int j = 0; j < 4; ++j)
      ys[p][c4 * 4 + j] = (float)a.h[j] + (float)b.h[j];
  }
  __syncthreads();

  float* ob = out + (size_t)(pair * 2 + img2) * OUT_C * HW + p0;
  for (int t = tid; t < OUT_C * 64; t += 256) {
    int c = t >> 6, p = t & 63;
    ob[(size_t)c * HW + p] = ys[p][c];
  }
}

extern "C" void kernel_launch(void* const* d_in, const int* in_sizes, int n_in,
                              void* d_out, int out_size, void* d_ws, size_t ws_size,
                              hipStream_t stream) {
  const float* x   = (const float*)d_in[0];
  const float* rin = (const float*)d_in[1];
  const float* rW  = (const float*)d_in[2];
  const float* rb  = (const float*)d_in[3];
  const float* W1  = (const float*)d_in[4];
  const float* b1  = (const float*)d_in[5];
  const float* W2  = (const float*)d_in[6];
  const float* b2  = (const float*)d_in[7];
  const float* W3  = (const float*)d_in[8];
  const float* b3  = (const float*)d_in[9];
  float* out = (float*)d_out;

  char* ws = (char*)d_ws;
  int*   counts = (int*)ws;
  int*   lists  = (int*)(ws + 1024);
  float* gatev  = (float*)(ws + 1024 + (size_t)NE * 4 * PPB * 4);
  _Float16* Wb  = (_Float16*)(ws + 1024 + 2 * (size_t)NE * 4 * PPB * 4);
  _Float16* ybuf = Wb + (size_t)NE * 294912;
  _Float16* xt = ybuf + (size_t)2 * PPB * 2 * 192;

  hipMemsetAsync(counts, 0, NE * 4 * sizeof(int), stream);

  // fused: cvt_blob (2304 blocks) | router (256) | xt pair0 (512)
  prologue_kernel<<<3072, 256, 0, stream>>>(W1, W2, W3, Wb,
                                            rin, rW, rb, counts, lists, gatev,
                                            x, xt);

  // pair 0: moe -> sum (sum also transposes x for pair 1 in extra blocks)
  moe_mfma_kernel<<<dim3(NE, 512), 384, 0, stream>>>(
      xt, Wb, b1, b2, b3, counts, lists, gatev, ybuf, 0);
  sum_kernel<<<1024, 256, 0, stream>>>(ybuf, out, 0, x, xt, 1);

  // pair 1: moe -> sum
  moe_mfma_kernel<<<dim3(NE, 512), 384, 0, stream>>>(
      xt, Wb, b1, b2, b3, counts, lists, gatev, ybuf, 1);
  sum_kernel<<<512, 256, 0, stream>>>(ybuf, out, 1, x, xt, 0);
}

// Round 23
// 233.596 us; speedup vs baseline: 1.3417x; 1.3417x over previous
//
#include <hip/hip_runtime.h>
#include <math.h>

#define NE 8
#define IN_C 192
#define HID 384
#define OUT_C 192
#define R_C 8
#define HW 16384
#define NPIX 65536
#define PPB 16384    // pixels per image
#define TNP 64       // pixels per moe block

typedef _Float16 h8_t __attribute__((ext_vector_type(8)));
typedef float f32x4 __attribute__((ext_vector_type(4)));

// A&S 7.1.26 erf (|abs err| <= 1.5e-7) -> exact-GELU within fp32 noise.
__device__ __forceinline__ float gelu_exact(float v) {
  float z  = v * 0.70710678118654752f;
  float az = fabsf(z);
  float t  = __builtin_amdgcn_rcpf(1.0f + 0.3275911f * az);
  float p  = ((((1.061405429f * t - 1.453152027f) * t + 1.421413741f) * t
               - 0.284496736f) * t + 0.254829592f) * t;
  float er = 1.0f - p * __expf(-z * z);
  er = copysignf(er, z);
  return 0.5f * v * (1.0f + er);
}

// ---------------------------------------------------------------------------
// x transpose helper (one image): xb [192][16384] fp32 -> dst [16384][192] f16
// ---------------------------------------------------------------------------
__device__ __forceinline__ void xt_block(const float* __restrict__ xb,
                                         _Float16* __restrict__ dst,
                                         int blk, int tid) {
  const int p = blk * 64 + (tid & 63);
  const int cq0 = tid >> 6;
#pragma unroll
  for (int cq = 0; cq < 6; ++cq) {
    int chq = cq * 4 + cq0;
    union { _Float16 h[8]; uint4 u; } pk;
#pragma unroll
    for (int j = 0; j < 8; ++j)
      pk.h[j] = (_Float16)xb[(size_t)(chq * 8 + j) * HW + p];
    *(uint4*)(dst + (size_t)p * 192 + chq * 8) = pk.u;
  }
}

// ---------------------------------------------------------------------------
// Fused prologue: blockIdx partitions three independent jobs.
//   [0, 2304): weight fp32 -> fp16 blob (consumption order, 48x12KB chunks,
//              chunk = [g:4][m:192][j:8], element (m, k0+8g+j))
//   [2304, 2560): router (LDS histogram + 1 global atomic per block/expert)
//   [2560, 3072): x transpose for pair 0 (img2 = blk>>8)
// ---------------------------------------------------------------------------
__global__ __launch_bounds__(256) void prologue_kernel(
    const float* __restrict__ W1, const float* __restrict__ W2,
    const float* __restrict__ W3, _Float16* __restrict__ Wb,
    const float* __restrict__ rin, const float* __restrict__ rW,
    const float* __restrict__ rb, int* __restrict__ counts,
    int* __restrict__ lists, float* __restrict__ gatev,
    const float* __restrict__ x, _Float16* __restrict__ xt) {
  const int bid = blockIdx.x;
  const int tid = threadIdx.x;

  __shared__ int lcount[NE];
  __shared__ int lbase[NE];

  if (bid < 2304) {
    // ---- cvt_blob ----
    int t = bid * 256 + tid;
    if (t >= NE * 73728) return;     // uint2 units: 48*1536 per expert
    int e = t / 73728, r = t % 73728;
    int cg = r / 1536, w = r % 1536;
    int j4 = w & 1, gm = w >> 1;
    int m = gm % 192, g = gm / 192;
    const float* src; int row, col, lda;
    if (cg < 6)       { src = W1 + (size_t)e * 73728;  row = m;       col = 32 * cg + 8 * g + 4 * j4; lda = 192; }
    else if (cg < 18) { int s = cg - 6;  int c = s >> 1, mh = s & 1;
                        src = W2 + (size_t)e * 147456; row = 192 * mh + m; col = 32 * c + 8 * g + 4 * j4; lda = 384; }
    else if (cg < 24) { int c = cg - 18;
                        src = W1 + (size_t)e * 73728;  row = 192 + m; col = 32 * c + 8 * g + 4 * j4; lda = 192; }
    else if (cg < 36) { int s = cg - 24; int c = s >> 1, mh = s & 1;
                        src = W2 + (size_t)e * 147456; row = 192 * mh + m; col = 192 + 32 * c + 8 * g + 4 * j4; lda = 384; }
    else              { int c = cg - 36;
                        src = W3 + (size_t)e * 73728;  row = m;       col = 32 * c + 8 * g + 4 * j4; lda = 384; }
    float4 v = *(const float4*)(src + (size_t)row * lda + col);
    union { _Float16 h4[4]; uint2 u; } cv;
    cv.h4[0] = (_Float16)v.x; cv.h4[1] = (_Float16)v.y;
    cv.h4[2] = (_Float16)v.z; cv.h4[3] = (_Float16)v.w;
    ((uint2*)Wb)[t] = cv.u;
  } else if (bid < 2560) {
    // ---- router ----
    const int pid = (bid - 2304) * 256 + tid;
    const int img = pid >> 14;
    const int p = pid & (PPB - 1);

    if (tid < NE) lcount[tid] = 0;
    __syncthreads();

    const float* rbase = rin + (size_t)img * R_C * HW + p;
    float r[R_C];
#pragma unroll
    for (int c = 0; c < R_C; ++c) r[c] = rbase[(size_t)c * HW];
    float lg[NE];
#pragma unroll
    for (int e = 0; e < NE; ++e) {
      float s = rb[e];
#pragma unroll
      for (int c = 0; c < R_C; ++c) s += rW[e * R_C + c] * r[c];
      lg[e] = s;
    }
    int e0 = 0; float l0 = lg[0];
#pragma unroll
    for (int e = 1; e < NE; ++e) { if (lg[e] > l0) { l0 = lg[e]; e0 = e; } }
    int e1 = -1; float l1 = -3.4e38f;
#pragma unroll
    for (int e = 0; e < NE; ++e) {
      if (e != e0 && lg[e] > l1) { l1 = lg[e]; e1 = e; }
    }
    float ex  = expf(l1 - l0);
    float inv = 1.0f / (1.0f + ex);
    float g0 = inv, g1 = ex * inv;

    int pos0 = atomicAdd(&lcount[e0], 1);
    int pos1 = atomicAdd(&lcount[e1], 1);
    __syncthreads();
    if (tid < NE) lbase[tid] = atomicAdd(&counts[tid * 4 + img], lcount[tid]);
    __syncthreads();

    int i0 = (e0 * 4 + img) * PPB + lbase[e0] + pos0;
    lists[i0] = p;
    gatev[i0] = g0;
    int i1 = (e1 * 4 + img) * PPB + lbase[e1] + pos1;
    lists[i1] = p | (1 << 14);
    gatev[i1] = g1;
  } else {
    // ---- xt for pair 0 ----
    const int b2 = bid - 2560;
    const int img2 = b2 >> 8;
    xt_block(x + (size_t)img2 * IN_C * HW,
             xt + (size_t)img2 * PPB * 192, b2 & 255, tid);
  }
}

// ---------------------------------------------------------------------------
// Stage one 12KB chunk: 8KB by all 8 waves + 4KB by waves 0-3.
// vmcnt cost per chunk: wid<4 -> 2, wid>=4 -> 1.
// ---------------------------------------------------------------------------
__device__ __forceinline__ void stage_chunk(const char* __restrict__ g,
                                            char* lds, int tid, int wid) {
  __builtin_amdgcn_global_load_lds(
      (const __attribute__((address_space(1))) void*)(g + tid * 16),
      (__attribute__((address_space(3))) void*)(lds + wid * 1024), 16, 0, 0);
  if (wid < 4)
    __builtin_amdgcn_global_load_lds(
        (const __attribute__((address_space(1))) void*)(g + 8192 + tid * 16),
        (__attribute__((address_space(3))) void*)(lds + 8192 + wid * 1024), 16, 0, 0);
}

// Phase entry: chunk s ready (s+1 stays in flight), then barrier.
__device__ __forceinline__ void pwait_c(int wid, bool last) {
  if (last)         asm volatile("s_waitcnt vmcnt(0)" ::: "memory");
  else if (wid < 4) asm volatile("s_waitcnt vmcnt(2)" ::: "memory");
  else              asm volatile("s_waitcnt vmcnt(1)" ::: "memory");
  __builtin_amdgcn_s_barrier();
  __builtin_amdgcn_sched_barrier(0);
}

// 2 B-fragments from LDS slot order [k8][64][8].
__device__ __forceinline__ void read_B2(const _Float16* __restrict__ Bsh, int kb4,
                                        int nt0, int l15, int g, h8_t (&b)[2]) {
#pragma unroll
  for (int t = 0; t < 2; ++t)
    b[t] = *(const h8_t*)(Bsh + (((size_t)(kb4 + g) * TNP) + (nt0 + t) * 16 + l15) * 8);
}

// 3x2 MFMA from ring chunk A [g][192][8] + B regs.
__device__ __forceinline__ void mfma32(const _Float16* __restrict__ A, const h8_t (&b)[2],
                                       int m0, f32x4 (&acc)[3][2], int l15, int g) {
  h8_t a[3];
#pragma unroll
  for (int i = 0; i < 3; ++i)
    a[i] = *(const h8_t*)(A + ((size_t)g * 192 + m0 + i * 16 + l15) * 8);
  __builtin_amdgcn_s_setprio(1);
#pragma unroll
  for (int i = 0; i < 3; ++i)
#pragma unroll
    for (int t = 0; t < 2; ++t)
      acc[i][t] = __builtin_amdgcn_mfma_f32_16x16x32_f16(a[i], b[t], acc[i][t], 0, 0, 0);
  __builtin_amdgcn_s_setprio(0);
}

__device__ __forceinline__ void act_store(f32x4 (&acc)[3][2], const float* __restrict__ bias,
                                          _Float16* __restrict__ Dst, int m0, int nt0, int lane) {
  const int l15 = lane & 15, g = lane >> 4;
#pragma unroll
  for (int i = 0; i < 3; ++i) {
    int rb = m0 + i * 16 + 4 * g;
    float4 bv = *(const float4*)(bias + rb);
#pragma unroll
    for (int t = 0; t < 2; ++t) {
      int n = (nt0 + t) * 16 + l15;
      union { _Float16 h[4]; uint2 u; } cv;
      cv.h[0] = (_Float16)gelu_exact(acc[i][t][0] + bv.x);
      cv.h[1] = (_Float16)gelu_exact(acc[i][t][1] + bv.y);
      cv.h[2] = (_Float16)gelu_exact(acc[i][t][2] + bv.z);
      cv.h[3] = (_Float16)gelu_exact(acc[i][t][3] + bv.w);
      *(uint2*)(Dst + (((size_t)(rb >> 3) * TNP) + n) * 8 + (rb & 7)) = cv.u;
    }
  }
}

__device__ __forceinline__ void ybuf_store(f32x4 (&acc)[3][2], const float* __restrict__ bias,
                                           _Float16* __restrict__ ybuf,
                                           const int* __restrict__ pidsl,
                                           const float* __restrict__ pg,
                                           int npt, int m0, int nt0, int lane) {
  const int l15 = lane & 15, g = lane >> 4;
#pragma unroll
  for (int t = 0; t < 2; ++t) {
    int n = (nt0 + t) * 16 + l15;
    if (n >= npt) continue;
    float gt = pg[n];
    _Float16* yb = ybuf + pidsl[n];
#pragma unroll
    for (int i = 0; i < 3; ++i) {
      int rb = m0 + i * 16 + 4 * g;
      float4 bv = *(const float4*)(bias + rb);
      union { _Float16 h[4]; uint2 u; } cv;
      cv.h[0] = (_Float16)((acc[i][t][0] + bv.x) * gt);
      cv.h[1] = (_Float16)((acc[i][t][1] + bv.y) * gt);
      cv.h[2] = (_Float16)((acc[i][t][2] + bv.z) * gt);
      cv.h[3] = (_Float16)((acc[i][t][3] + bv.w) * gt);
      *(uint2*)(yb + rb) = cv.u;
    }
  }
}

// ---------------------------------------------------------------------------
// Fused 3-layer MLP, 64-pixel tile, 8 waves, 48 single-chunk phases over a
// 2x12KB ring. LDS 76.5KB -> 2 blocks/CU (4 waves/SIMD).
// Depth-1 prefetch invariant: the phase computing chunk c stages chunk c+2.
// ---------------------------------------------------------------------------
__global__ __launch_bounds__(512, 4) void moe_mfma_kernel(
    const _Float16* __restrict__ xt, const _Float16* __restrict__ Wb,
    const float* __restrict__ b1, const float* __restrict__ b2,
    const float* __restrict__ b3,
    const int* __restrict__ counts, const int* __restrict__ lists,
    const float* __restrict__ gatev, _Float16* __restrict__ ybuf, int pair) {
  const int e = blockIdx.x;
  const int img2 = blockIdx.y >> 8;
  const int tile = blockIdx.y & 255;
  const int img = pair * 2 + img2;
  const int cnt = counts[e * 4 + img];
  const int start = tile * TNP;
  if (start >= cnt) return;
  const int npt = min(TNP, cnt - start);

  __shared__ __align__(16) char smem[78336];
  _Float16* XB  = (_Float16*)smem;                 // [24][64][8] 24K
  _Float16* H1a = (_Float16*)(smem + 24576);       // [24][64][8] 24K
  _Float16* H2  = (_Float16*)smem;                 // [48][64][8] 48K alias
  char* RING   = smem + 49152;                     // 2 x 12K
  float* BIAS1 = (float*)(smem + 73728);
  float* BIAS2 = (float*)(smem + 75264);
  float* BIAS3 = (float*)(smem + 76800);
  int*   pp    = (int*)(smem + 77568);
  int*   pidsl = (int*)(smem + 77824);
  float* pg    = (float*)(smem + 78080);

  const int tid = threadIdx.x;
  const int lane = tid & 63;
  const int wid = tid >> 6;
  const int l15 = lane & 15;
  const int g = lane >> 4;
  const int m0loc = (wid >> 1) * 48;
  const int nt0 = (wid & 1) * 2;

  // ---- prologue: lists, biases, x-gather ----
  if (tid < TNP) {
    int entry = 0; float gt = 0.0f;
    if (tid < npt) {
      entry = lists[(e * 4 + img) * PPB + start + tid];
      gt    = gatev[(e * 4 + img) * PPB + start + tid];
    }
    int p = entry & (PPB - 1);
    int slot = (entry >> 14) & 1;
    pp[tid] = img2 * PPB + p;
    pidsl[tid] = ((img2 * PPB + p) * 2 + slot) * 192;
    pg[tid] = gt;
  }
  for (int i = tid; i < 960; i += 512) {
    if (i < 384) BIAS1[i] = b1[e * HID + i];
    else if (i < 768) BIAS2[i - 384] = b2[e * HID + (i - 384)];
    else BIAS3[i - 768] = b3[e * OUT_C + (i - 768)];
  }
  __syncthreads();

  for (int i = tid; i < 24 * TNP; i += 512) {   // 3 iterations
    int n = i & (TNP - 1);
    int c16 = i >> 6;
    uint4 v = {0, 0, 0, 0};
    if (n < npt) v = *(const uint4*)(xt + (size_t)pp[n] * 192 + c16 * 8);
    *(uint4*)(XB + ((size_t)c16 * TNP + n) * 8) = v;
  }
  __syncthreads();   // drains gather vmem; only stage loads counted below

  const char* blob = (const char*)(Wb + (size_t)e * 294912);
  stage_chunk(blob, RING, tid, wid);
  stage_chunk(blob + 12288, RING + 12288, tid, wid);

  f32x4 acc1[3][2], acc2a[3][2], acc2b[3][2];
#pragma unroll
  for (int i = 0; i < 3; ++i)
#pragma unroll
    for (int t = 0; t < 2; ++t) {
      acc1[i][t] = (f32x4){0.f, 0.f, 0.f, 0.f};
      acc2a[i][t] = (f32x4){0.f, 0.f, 0.f, 0.f};
      acc2b[i][t] = (f32x4){0.f, 0.f, 0.f, 0.f};
    }

  h8_t b[2];

  // ---- seg A: chunks 0..5, L1 half0, B=XB kb4=4s ----
#pragma unroll
  for (int s = 0; s < 6; ++s) {
    pwait_c(wid, false);
    read_B2(XB, 4 * s, nt0, l15, g, b);
    mfma32((const _Float16*)(RING + (s & 1) * 12288), b, m0loc, acc1, l15, g);
    if (s == 5) {
      act_store(acc1, BIAS1, H1a, m0loc, nt0, lane);
      asm volatile("s_waitcnt lgkmcnt(0)");
    }
    __builtin_amdgcn_sched_barrier(0);
    __builtin_amdgcn_s_barrier();
    __builtin_amdgcn_sched_barrier(0);
    stage_chunk(blob + (size_t)(s + 2) * 12288, RING + (s & 1) * 12288, tid, wid);
  }

  // ---- seg B: chunks 6..17, L2 kh0, B=H1a kb4=4*(s>>1), acc by mh=s&1 ----
#pragma unroll
  for (int s = 0; s < 12; ++s) {
    pwait_c(wid, false);
    if ((s & 1) == 0) read_B2(H1a, 4 * (s >> 1), nt0, l15, g, b);
    mfma32((const _Float16*)(RING + (s & 1) * 12288), b, m0loc,
           (s & 1) ? acc2b : acc2a, l15, g);
    __builtin_amdgcn_sched_barrier(0);
    __builtin_amdgcn_s_barrier();
    __builtin_amdgcn_sched_barrier(0);
    stage_chunk(blob + (size_t)(s + 8) * 12288, RING + (s & 1) * 12288, tid, wid);
  }

  // ---- seg C: chunks 18..23, L1 half1 (stage s+20) ----
#pragma unroll
  for (int i = 0; i < 3; ++i)
#pragma unroll
    for (int t = 0; t < 2; ++t) acc1[i][t] = (f32x4){0.f, 0.f, 0.f, 0.f};
#pragma unroll
  for (int s = 0; s < 6; ++s) {
    pwait_c(wid, false);
    read_B2(XB, 4 * s, nt0, l15, g, b);
    mfma32((const _Float16*)(RING + (s & 1) * 12288), b, m0loc, acc1, l15, g);
    if (s == 5) {
      act_store(acc1, BIAS1 + 192, H1a, m0loc, nt0, lane);
      asm volatile("s_waitcnt lgkmcnt(0)");
    }
    __builtin_amdgcn_sched_barrier(0);
    __builtin_amdgcn_s_barrier();
    __builtin_amdgcn_sched_barrier(0);
    stage_chunk(blob + (size_t)(s + 20) * 12288, RING + (s & 1) * 12288, tid, wid);
  }

  // ---- seg D: chunks 24..35, L2 kh1 (stage s+26) ----
#pragma unroll
  for (int s = 0; s < 12; ++s) {
    pwait_c(wid, false);
    if ((s & 1) == 0) read_B2(H1a, 4 * (s >> 1), nt0, l15, g, b);
    mfma32((const _Float16*)(RING + (s & 1) * 12288), b, m0loc,
           (s & 1) ? acc2b : acc2a, l15, g);
    if (s == 11) {
      act_store(acc2a, BIAS2, H2, m0loc, nt0, lane);
      act_store(acc2b, BIAS2, H2, 192 + m0loc, nt0, lane);
      asm volatile("s_waitcnt lgkmcnt(0)");
    }
    __builtin_amdgcn_sched_barrier(0);
    __builtin_amdgcn_s_barrier();
    __builtin_amdgcn_sched_barrier(0);
    stage_chunk(blob + (size_t)(s + 26) * 12288, RING + (s & 1) * 12288, tid, wid);
  }

  // ---- seg E: chunks 36..47, L3 over H2, kb4=4s (stage s+38, s<10) ----
#pragma unroll
  for (int i = 0; i < 3; ++i)
#pragma unroll
    for (int t = 0; t < 2; ++t) acc1[i][t] = (f32x4){0.f, 0.f, 0.f, 0.f};
#pragma unroll
  for (int s = 0; s < 12; ++s) {
    pwait_c(wid, s == 11);
    read_B2(H2, 4 * s, nt0, l15, g, b);
    mfma32((const _Float16*)(RING + (s & 1) * 12288), b, m0loc, acc1, l15, g);
    if (s < 10) {
      __builtin_amdgcn_sched_barrier(0);
      __builtin_amdgcn_s_barrier();
      __builtin_amdgcn_sched_barrier(0);
      stage_chunk(blob + (size_t)(s + 38) * 12288, RING + (s & 1) * 12288, tid, wid);
    }
  }

  ybuf_store(acc1, BIAS3, ybuf, pidsl, pg, npt, m0loc, nt0, lane);
}

// ---------------------------------------------------------------------------
// Sum the two gated slot results per pixel, write out coalesced.
// If XTP1 != 0, blocks [512, 1024) additionally transpose x for pair 1
// (safe: xt for pair 0 is fully consumed by the preceding moe dispatch).
// ---------------------------------------------------------------------------
__global__ __launch_bounds__(256) void sum_kernel(
    const _Float16* __restrict__ ybuf, float* __restrict__ out, int pair,
    const float* __restrict__ x, _Float16* __restrict__ xt, int xtp1) {
  __shared__ float ys[64][193];
  const int tid = threadIdx.x;

  if (xtp1 && blockIdx.x >= 512) {
    const int b2 = blockIdx.x - 512;
    const int img2 = b2 >> 8;
    xt_block(x + (size_t)(2 + img2) * IN_C * HW,
             xt + (size_t)img2 * PPB * 192, b2 & 255, tid);
    return;
  }

  const int img2 = blockIdx.x >> 8;
  const int p0 = (blockIdx.x & 255) * 64;
  const _Float16* yb = ybuf + (size_t)(img2 * PPB + p0) * 2 * 192;

  for (int t = tid; t < 64 * 48; t += 256) {
    int p = t / 48, c4 = t % 48;
    const uint2* y0 = (const uint2*)(yb + (size_t)p * 2 * 192) + c4;
    uint2 u0 = y0[0];
    uint2 u1 = y0[48];
    union { uint2 u; _Float16 h[4]; } a, b;
    a.u = u0; b.u = u1;
#pragma unroll
    for (int j = 0; j < 4; ++j)
      ys[p][c4 * 4 + j] = (float)a.h[j] + (float)b.h[j];
  }
  __syncthreads();

  float* ob = out + (size_t)(pair * 2 + img2) * OUT_C * HW + p0;
  for (int t = tid; t < OUT_C * 64; t += 256) {
    int c = t >> 6, p = t & 63;
    ob[(size_t)c * HW + p] = ys[p][c];
  }
}

extern "C" void kernel_launch(void* const* d_in, const int* in_sizes, int n_in,
                              void* d_out, int out_size, void* d_ws, size_t ws_size,
                              hipStream_t stream) {
  const float* x   = (const float*)d_in[0];
  const float* rin = (const float*)d_in[1];
  const float* rW  = (const float*)d_in[2];
  const float* rb  = (const float*)d_in[3];
  const float* W1  = (const float*)d_in[4];
  const float* b1  = (const float*)d_in[5];
  const float* W2  = (const float*)d_in[6];
  const float* b2  = (const float*)d_in[7];
  const float* W3  = (const float*)d_in[8];
  const float* b3  = (const float*)d_in[9];
  float* out = (float*)d_out;

  char* ws = (char*)d_ws;
  int*   counts = (int*)ws;
  int*   lists  = (int*)(ws + 1024);
  float* gatev  = (float*)(ws + 1024 + (size_t)NE * 4 * PPB * 4);
  _Float16* Wb  = (_Float16*)(ws + 1024 + 2 * (size_t)NE * 4 * PPB * 4);
  _Float16* ybuf = Wb + (size_t)NE * 294912;
  _Float16* xt = ybuf + (size_t)2 * PPB * 2 * 192;

  hipMemsetAsync(counts, 0, NE * 4 * sizeof(int), stream);

  // fused: cvt_blob (2304 blocks) | router (256) | xt pair0 (512)
  prologue_kernel<<<3072, 256, 0, stream>>>(W1, W2, W3, Wb,
                                            rin, rW, rb, counts, lists, gatev,
                                            x, xt);

  // pair 0: moe -> sum (sum also transposes x for pair 1 in extra blocks)
  moe_mfma_kernel<<<dim3(NE, 512), 512, 0, stream>>>(
      xt, Wb, b1, b2, b3, counts, lists, gatev, ybuf, 0);
  sum_kernel<<<1024, 256, 0, stream>>>(ybuf, out, 0, x, xt, 1);

  // pair 1: moe -> sum
  moe_mfma_kernel<<<dim3(NE, 512), 512, 0, stream>>>(
      xt, Wb, b1, b2, b3, counts, lists, gatev, ybuf, 1);
  sum_kernel<<<512, 256, 0, stream>>>(ybuf, out, 1, x, xt, 0);
}